// Round 1
// baseline (1516.988 us; speedup 1.0000x reference)
//
#include <hip/hip_runtime.h>
#include <cstddef>
#include <cstdint>

#define B_ 64
#define S_ 4096
#define D_ 1024
#define NBLK 16                 /* pass1 blocks per batch */
#define WAVES 4                 /* waves per block */
#define NCH (NBLK * WAVES)      /* 64 independent wave-chunks per batch */
#define WROWS (S_ / NCH)        /* 64 rows per wave-chunk */

__device__ __forceinline__ float dot4(float4 a, float4 b) {
    return a.x * b.x + a.y * b.y + a.z * b.z + a.w * b.w;
}

// ---------------------------------------------------------------------------
// Small GEMM: C[b,i] = act( sum_d A1[b,d]*W1[i,d] (+ sum_d A2[b,d]*W2[i,d]) )
// A*: [64,1024] row-major, W*: [1024,1024] row-major (we need A @ W^T).
// grid = 256 blocks (4 output columns each), block = 256 threads (1 out/thread)
// 4 independent accumulators: at 1 wave/SIMD occupancy the single dependent
// FMA chain was the serializer; this quadruples ILP and load depth.
// ---------------------------------------------------------------------------
__global__ __launch_bounds__(256) void small_gemm(
    const float* __restrict__ A1, const float* __restrict__ W1,
    const float* __restrict__ A2, const float* __restrict__ W2,
    float* __restrict__ C, int do_tanh)
{
    int t = threadIdx.x;
    int i = blockIdx.x * 4 + (t & 3);
    int b = t >> 2;

    const float4* A14 = (const float4*)(A1 + (size_t)b * D_);
    const float4* W14 = (const float4*)(W1 + (size_t)i * D_);
    float acc0 = 0.f, acc1 = 0.f, acc2 = 0.f, acc3 = 0.f;
#pragma unroll 2
    for (int k = 0; k < D_ / 4; k += 4) {
        float4 a0 = A14[k + 0], w0 = W14[k + 0];
        float4 a1 = A14[k + 1], w1 = W14[k + 1];
        float4 a2 = A14[k + 2], w2 = W14[k + 2];
        float4 a3 = A14[k + 3], w3 = W14[k + 3];
        acc0 += dot4(a0, w0);
        acc1 += dot4(a1, w1);
        acc2 += dot4(a2, w2);
        acc3 += dot4(a3, w3);
    }
    if (A2 != nullptr) {
        const float4* A24 = (const float4*)(A2 + (size_t)b * D_);
        const float4* W24 = (const float4*)(W2 + (size_t)i * D_);
#pragma unroll 2
        for (int k = 0; k < D_ / 4; k += 4) {
            float4 a0 = A24[k + 0], w0 = W24[k + 0];
            float4 a1 = A24[k + 1], w1 = W24[k + 1];
            float4 a2 = A24[k + 2], w2 = W24[k + 2];
            float4 a3 = A24[k + 3], w3 = W24[k + 3];
            acc0 += dot4(a0, w0);
            acc1 += dot4(a1, w1);
            acc2 += dot4(a2, w2);
            acc3 += dot4(a3, w3);
        }
    }
    float acc = (acc0 + acc1) + (acc2 + acc3);
    if (do_tanh) acc = tanhf(acc);
    C[(size_t)b * D_ + i] = acc;
}

// ---------------------------------------------------------------------------
// Pass 1: fused scores + online-softmax weighted accumulation.
// BARRIER-FREE: each of the 4 waves in a block owns an independent 64-row
// chunk. Lane l owns d = {4l, 4l+1, 4l+2, 4l+3} + 256*j for j=0..3
// (coalesced 1 KB per (row, j) quarter). Score reduction is a 6-level
// __shfl_xor butterfly (all lanes receive the sum; no LDS, no syncthreads),
// so loads for the next 4-row group stay in flight across the reduction.
// Context is read exactly once from HBM.
// grid = (NBLK, B), block = 256.
// ---------------------------------------------------------------------------
__global__ __launch_bounds__(256) void pass1(
    const float* __restrict__ ctx,   // [B,S,D]
    const int* __restrict__ mask,    // [B,S]
    const float* __restrict__ q,     // [B,D]
    float* __restrict__ align_out,   // [B,S] raw masked scores
    float* __restrict__ pm,          // [B*NCH]
    float* __restrict__ pl,          // [B*NCH]
    float* __restrict__ pacc)        // [B*NCH, D]
{
    int b = blockIdx.y;
    int lane = threadIdx.x & 63;
    int c = blockIdx.x * WAVES + (threadIdx.x >> 6);   // wave-chunk 0..63

    const float4* qb = (const float4*)(q + (size_t)b * D_);
    float4 q0 = qb[lane];
    float4 q1 = qb[lane + 64];
    float4 q2 = qb[lane + 128];
    float4 q3 = qb[lane + 192];

    const float4* cb = (const float4*)(ctx + (size_t)b * S_ * D_ + (size_t)c * WROWS * D_);
    const int* mb = mask + (size_t)b * S_ + c * WROWS;
    float* ab = align_out + (size_t)b * S_ + c * WROWS;

    float m = -1e30f, l = 0.f;
    float4 a0 = make_float4(0.f, 0.f, 0.f, 0.f);
    float4 a1 = a0, a2 = a0, a3 = a0;

    for (int r0 = 0; r0 < WROWS; r0 += 4) {
        const float4* row0 = cb + (size_t)(r0 + 0) * (D_ / 4);
        const float4* row1 = cb + (size_t)(r0 + 1) * (D_ / 4);
        const float4* row2 = cb + (size_t)(r0 + 2) * (D_ / 4);
        const float4* row3 = cb + (size_t)(r0 + 3) * (D_ / 4);

        float4 v00 = row0[lane], v01 = row0[lane + 64], v02 = row0[lane + 128], v03 = row0[lane + 192];
        float4 v10 = row1[lane], v11 = row1[lane + 64], v12 = row1[lane + 128], v13 = row1[lane + 192];
        float4 v20 = row2[lane], v21 = row2[lane + 64], v22 = row2[lane + 128], v23 = row2[lane + 192];
        float4 v30 = row3[lane], v31 = row3[lane + 64], v32 = row3[lane + 128], v33 = row3[lane + 192];

        int mk0 = mb[r0 + 0], mk1 = mb[r0 + 1], mk2 = mb[r0 + 2], mk3 = mb[r0 + 3];

        float p0 = dot4(v00, q0) + dot4(v01, q1) + dot4(v02, q2) + dot4(v03, q3);
        float p1 = dot4(v10, q0) + dot4(v11, q1) + dot4(v12, q2) + dot4(v13, q3);
        float p2 = dot4(v20, q0) + dot4(v21, q1) + dot4(v22, q2) + dot4(v23, q3);
        float p3 = dot4(v30, q0) + dot4(v31, q1) + dot4(v32, q2) + dot4(v33, q3);

#pragma unroll
        for (int off = 32; off > 0; off >>= 1) {
            p0 += __shfl_xor(p0, off);
            p1 += __shfl_xor(p1, off);
            p2 += __shfl_xor(p2, off);
            p3 += __shfl_xor(p3, off);
        }

        float s0 = mk0 ? p0 : -1e30f;
        float s1 = mk1 ? p1 : -1e30f;
        float s2 = mk2 ? p2 : -1e30f;
        float s3 = mk3 ? p3 : -1e30f;

        float sv = (lane == 0) ? s0 : (lane == 1) ? s1 : (lane == 2) ? s2 : s3;
        if (lane < 4) ab[r0 + lane] = sv;

        float nm = fmaxf(m, fmaxf(fmaxf(s0, s1), fmaxf(s2, s3)));
        float alpha = expf(m - nm); // m==-1e30 & nm real -> 0; both -1e30 -> 1
        float e0 = (s0 <= -1e29f) ? 0.f : expf(s0 - nm);
        float e1 = (s1 <= -1e29f) ? 0.f : expf(s1 - nm);
        float e2 = (s2 <= -1e29f) ? 0.f : expf(s2 - nm);
        float e3 = (s3 <= -1e29f) ? 0.f : expf(s3 - nm);

        l = l * alpha + (e0 + e1 + e2 + e3);

        a0.x = a0.x * alpha + e0 * v00.x + e1 * v10.x + e2 * v20.x + e3 * v30.x;
        a0.y = a0.y * alpha + e0 * v00.y + e1 * v10.y + e2 * v20.y + e3 * v30.y;
        a0.z = a0.z * alpha + e0 * v00.z + e1 * v10.z + e2 * v20.z + e3 * v30.z;
        a0.w = a0.w * alpha + e0 * v00.w + e1 * v10.w + e2 * v20.w + e3 * v30.w;

        a1.x = a1.x * alpha + e0 * v01.x + e1 * v11.x + e2 * v21.x + e3 * v31.x;
        a1.y = a1.y * alpha + e0 * v01.y + e1 * v11.y + e2 * v21.y + e3 * v31.y;
        a1.z = a1.z * alpha + e0 * v01.z + e1 * v11.z + e2 * v21.z + e3 * v31.z;
        a1.w = a1.w * alpha + e0 * v01.w + e1 * v11.w + e2 * v21.w + e3 * v31.w;

        a2.x = a2.x * alpha + e0 * v02.x + e1 * v12.x + e2 * v22.x + e3 * v32.x;
        a2.y = a2.y * alpha + e0 * v02.y + e1 * v12.y + e2 * v22.y + e3 * v32.y;
        a2.z = a2.z * alpha + e0 * v02.z + e1 * v12.z + e2 * v22.z + e3 * v32.z;
        a2.w = a2.w * alpha + e0 * v02.w + e1 * v12.w + e2 * v22.w + e3 * v32.w;

        a3.x = a3.x * alpha + e0 * v03.x + e1 * v13.x + e2 * v23.x + e3 * v33.x;
        a3.y = a3.y * alpha + e0 * v03.y + e1 * v13.y + e2 * v23.y + e3 * v33.y;
        a3.z = a3.z * alpha + e0 * v03.z + e1 * v13.z + e2 * v23.z + e3 * v33.z;
        a3.w = a3.w * alpha + e0 * v03.w + e1 * v13.w + e2 * v23.w + e3 * v33.w;

        m = nm;
    }

    int idx = b * NCH + c;
    if (lane == 0) {
        pm[idx] = m;
        pl[idx] = l;
    }
    float4* pa = (float4*)(pacc + (size_t)idx * D_);
    pa[lane] = a0;
    pa[lane + 64] = a1;
    pa[lane + 128] = a2;
    pa[lane + 192] = a3;
}

// ---------------------------------------------------------------------------
// Combine chunk partials: wc[b,d] = sum_c acc_c[d]*exp(m_c-m)/l ; store (m,l).
// grid = B, block = 256 (thread t owns d = 4t..4t+3). NCH=64 chunks.
// ---------------------------------------------------------------------------
__global__ __launch_bounds__(256) void combine(
    const float* __restrict__ pm, const float* __restrict__ pl,
    const float* __restrict__ pacc,
    float* __restrict__ wc, float* __restrict__ ml)
{
    int b = blockIdx.x, t = threadIdx.x;
    const float* pmb = pm + (size_t)b * NCH;
    const float* plb = pl + (size_t)b * NCH;

    float m = -1e30f;
#pragma unroll
    for (int c = 0; c < NCH; ++c) m = fmaxf(m, pmb[c]);

    float l = 0.f;
    float ax = 0.f, ay = 0.f, az = 0.f, aw = 0.f;
    const float4* pb = (const float4*)(pacc + (size_t)b * NCH * D_);
#pragma unroll 4
    for (int c = 0; c < NCH; ++c) {
        float w = expf(pmb[c] - m);
        l += plb[c] * w;
        float4 a = pb[(size_t)c * (D_ / 4) + t];
        ax += a.x * w;
        ay += a.y * w;
        az += a.z * w;
        aw += a.w * w;
    }
    float inv = (l > 0.f) ? 1.f / l : 0.f;
    float4 r;
    r.x = ax * inv; r.y = ay * inv; r.z = az * inv; r.w = aw * inv;
    ((float4*)(wc + (size_t)b * D_))[t] = r;
    if (t == 0) {
        ml[b * 2 + 0] = m;
        ml[b * 2 + 1] = l;
    }
}

// ---------------------------------------------------------------------------
// Rewrite raw scores -> softmax probabilities in place.
// ---------------------------------------------------------------------------
__global__ __launch_bounds__(256) void finalize_att(
    float* __restrict__ att, const float* __restrict__ ml)
{
    int idx = blockIdx.x * 256 + threadIdx.x;
    int b = idx >> 12; // / S_
    float s = att[idx];
    float m = ml[b * 2 + 0], l = ml[b * 2 + 1];
    float v = (s <= -1e29f || !(l > 0.f)) ? 0.f : expf(s - m) / l;
    att[idx] = v;
}

// ---------------------------------------------------------------------------
extern "C" void kernel_launch(void* const* d_in, const int* in_sizes, int n_in,
                              void* d_out, int out_size, void* d_ws, size_t ws_size,
                              hipStream_t stream)
{
    const float* query     = (const float*)d_in[0]; // [B,D]
    const float* ctx       = (const float*)d_in[1]; // [B,S,D]
    const int*   mask      = (const int*)d_in[2];   // [B,S]
    const float* W_align   = (const float*)d_in[3]; // [D,D]
    const float* W_context = (const float*)d_in[4]; // [D,D]
    const float* W_query   = (const float*)d_in[5]; // [D,D]

    float* out = (float*)d_out;        // [B,D]   (65536)
    float* att = out + B_ * D_;        // [B,S]   (262144)
    float* wc  = att + B_ * S_;        // [B,D]   (65536)

    float* ws    = (float*)d_ws;
    float* qproj = ws;                       // B*D        = 65536 floats
    float* pm    = qproj + B_ * D_;          // B*NCH      = 4096
    float* pl    = pm + B_ * NCH;            // 4096
    float* ml    = pl + B_ * NCH;            // 128
    float* pacc  = ml + 2 * B_;              // B*NCH*D    = 4M floats (16 MB)

    // K1: q = query @ W_align^T
    small_gemm<<<dim3(D_ / 4), 256, 0, stream>>>(query, W_align, nullptr, nullptr, qproj, 0);

    // K2: fused scores + online softmax accumulation (single context pass,
    //     barrier-free, wave-independent chunks)
    pass1<<<dim3(NBLK, B_), 256, 0, stream>>>(ctx, mask, qproj, att, pm, pl, pacc);

    // K3: merge chunk partials -> weight_context + per-batch (m,l)
    combine<<<dim3(B_), 256, 0, stream>>>(pm, pl, pacc, wc, ml);

    // K4: scores -> attention probabilities
    finalize_att<<<dim3(B_ * S_ / 256), 256, 0, stream>>>(att, ml);

    // K5: out = tanh(wc @ W_context^T + query @ W_query^T)
    small_gemm<<<dim3(D_ / 4), 256, 0, stream>>>(wc, W_context, query, W_query, out, 1);
}